// Round 3
// baseline (20.226 us; speedup 1.0000x reference)
//
#include <hip/hip_runtime.h>
#include <hip/hip_bf16.h>

// HypeEntropyModelSoS: symbols = argmin_l |(x - means) - codebook[l]|,
//                      dequant = codebook[symbols] + means
// codebook is SORTED (L=64) -> branchless binary search (lower_bound) + exact
// 2-candidate |z-c| compare reproduces jnp.argmin first-tie semantics exactly.
//
// R2 -> R3: same plan as R2 (even split, 8 elem/thread, nt loads/stores) but
// with clang ext_vector float4 (HIP_vector_type structs are rejected by the
// nontemporal builtins).

#define LVLS 64

typedef float f32x4 __attribute__((ext_vector_type(4)));

__global__ __launch_bounds__(256) void quant_sos_kernel(
    const float* __restrict__ x,
    const float* __restrict__ means,
    const float* __restrict__ codebook,
    float* __restrict__ out_sym,   // symbols written as float values
    float* __restrict__ out_deq,
    int n8)                        // number of 8-element chunks
{
    __shared__ float cb[LVLS];
    if (threadIdx.x < LVLS) cb[threadIdx.x] = codebook[threadIdx.x];
    __syncthreads();

    int tid = blockIdx.x * blockDim.x + threadIdx.x;
    if (tid >= n8) return;

    const f32x4* __restrict__ x4 = (const f32x4*)x;
    const f32x4* __restrict__ m4 = (const f32x4*)means;
    f32x4* __restrict__ s4 = (f32x4*)out_sym;
    f32x4* __restrict__ d4 = (f32x4*)out_deq;

    long i0 = (long)tid * 2;
    f32x4 xa = __builtin_nontemporal_load(&x4[i0]);
    f32x4 xb = __builtin_nontemporal_load(&x4[i0 + 1]);
    f32x4 ma = __builtin_nontemporal_load(&m4[i0]);
    f32x4 mb = __builtin_nontemporal_load(&m4[i0 + 1]);

    float z[8]  = {xa.x - ma.x, xa.y - ma.y, xa.z - ma.z, xa.w - ma.w,
                   xb.x - mb.x, xb.y - mb.y, xb.z - mb.z, xb.w - mb.w};
    float mm[8] = {ma.x, ma.y, ma.z, ma.w, mb.x, mb.y, mb.z, mb.w};
    float sym[8], deq[8];

#pragma unroll
    for (int j = 0; j < 8; ++j) {
        float zj = z[j];
        // branchless lower_bound: pos = #elements with cb[k] < zj
        int pos = 0;
#pragma unroll
        for (int step = 32; step >= 1; step >>= 1) {
            pos = (cb[pos + step - 1] < zj) ? (pos + step) : pos;
        }
        // candidates pos-1 and pos, clamped; exact f32 distance compare,
        // tie -> lower index (matches jnp.argmin first-min semantics)
        int lo = (pos > 0)    ? pos - 1 : 0;
        int hi = (pos < LVLS) ? pos     : LVLS - 1;
        float clo = cb[lo];
        float chi = cb[hi];
        float dlo = fabsf(zj - clo);
        float dhi = fabsf(zj - chi);
        int   idx;
        float cval;
        if (dhi < dlo) { idx = hi; cval = chi; }
        else           { idx = lo; cval = clo; }
        sym[j] = (float)idx;
        deq[j] = cval + mm[j];
    }

    f32x4 sa = {sym[0], sym[1], sym[2], sym[3]};
    f32x4 sb = {sym[4], sym[5], sym[6], sym[7]};
    f32x4 da = {deq[0], deq[1], deq[2], deq[3]};
    f32x4 db = {deq[4], deq[5], deq[6], deq[7]};
    __builtin_nontemporal_store(sa, &s4[i0]);
    __builtin_nontemporal_store(sb, &s4[i0 + 1]);
    __builtin_nontemporal_store(da, &d4[i0]);
    __builtin_nontemporal_store(db, &d4[i0 + 1]);
}

extern "C" void kernel_launch(void* const* d_in, const int* in_sizes, int n_in,
                              void* d_out, int out_size, void* d_ws, size_t ws_size,
                              hipStream_t stream) {
    const float* x        = (const float*)d_in[0];
    const float* means    = (const float*)d_in[1];
    const float* codebook = (const float*)d_in[2];

    int n  = in_sizes[0];          // 4,718,592 (divisible by 8)
    int n8 = n >> 3;               // 589,824

    float* out_sym = (float*)d_out;        // first n floats: symbols (as float)
    float* out_deq = (float*)d_out + n;    // next n floats: dequant

    int block = 256;
    int grid  = (n8 + block - 1) / block;  // 2304 exactly

    quant_sos_kernel<<<grid, block, 0, stream>>>(x, means, codebook,
                                                 out_sym, out_deq, n8);
}

// Round 4
// 17.536 us; speedup vs baseline: 1.1534x; 1.1534x over previous
//
#include <hip/hip_runtime.h>
#include <hip/hip_bf16.h>

// HypeEntropyModelSoS: symbols = argmin_l |(x - means) - codebook[l]|,
//                      dequant = codebook[symbols] + means
// codebook is SORTED (L=64) -> branchless binary search (lower_bound) + exact
// 2-candidate |z-c| compare reproduces jnp.argmin first-tie semantics exactly.
//
// R3 -> R4: (a) restore perfect per-instruction coalescing: lane l of wave w
// handles float4 chunks w*128+l and w*128+64+l (each load/store instruction
// covers one contiguous 1KB segment — R3's i0=2*tid pattern spanned 2KB);
// (b) drop nontemporal hints (75MB working set is L3-resident across graph
// replays; nt forfeits L3 hits); (c) keep exact even split: 2304 blocks,
// 8 elem/thread, no grid-stride loop, no tail.

#define LVLS 64

typedef float f32x4 __attribute__((ext_vector_type(4)));

__global__ __launch_bounds__(256) void quant_sos_kernel(
    const float* __restrict__ x,
    const float* __restrict__ means,
    const float* __restrict__ codebook,
    float* __restrict__ out_sym,   // symbols written as float values
    float* __restrict__ out_deq,
    int nwave)                     // total waves = n4 / 128
{
    __shared__ float cb[LVLS];
    if (threadIdx.x < LVLS) cb[threadIdx.x] = codebook[threadIdx.x];
    __syncthreads();

    int tid  = blockIdx.x * blockDim.x + threadIdx.x;
    int w    = tid >> 6;
    int lane = tid & 63;
    if (w >= nwave) return;

    const f32x4* __restrict__ x4 = (const f32x4*)x;
    const f32x4* __restrict__ m4 = (const f32x4*)means;
    f32x4* __restrict__ s4 = (f32x4*)out_sym;
    f32x4* __restrict__ d4 = (f32x4*)out_deq;

    long cA = (long)w * 128 + lane;   // contiguous across lanes
    long cB = cA + 64;                // contiguous across lanes

    f32x4 xa = x4[cA];
    f32x4 xb = x4[cB];
    f32x4 ma = m4[cA];
    f32x4 mb = m4[cB];

    float z[8]  = {xa.x - ma.x, xa.y - ma.y, xa.z - ma.z, xa.w - ma.w,
                   xb.x - mb.x, xb.y - mb.y, xb.z - mb.z, xb.w - mb.w};
    float mm[8] = {ma.x, ma.y, ma.z, ma.w, mb.x, mb.y, mb.z, mb.w};
    float sym[8], deq[8];

#pragma unroll
    for (int j = 0; j < 8; ++j) {
        float zj = z[j];
        // branchless lower_bound: pos = #elements with cb[k] < zj
        int pos = 0;
#pragma unroll
        for (int step = 32; step >= 1; step >>= 1) {
            pos = (cb[pos + step - 1] < zj) ? (pos + step) : pos;
        }
        // candidates pos-1 and pos, clamped; exact f32 distance compare,
        // tie -> lower index (matches jnp.argmin first-min semantics)
        int lo = (pos > 0)    ? pos - 1 : 0;
        int hi = (pos < LVLS) ? pos     : LVLS - 1;
        float clo = cb[lo];
        float chi = cb[hi];
        float dlo = fabsf(zj - clo);
        float dhi = fabsf(zj - chi);
        int   idx;
        float cval;
        if (dhi < dlo) { idx = hi; cval = chi; }
        else           { idx = lo; cval = clo; }
        sym[j] = (float)idx;
        deq[j] = cval + mm[j];
    }

    f32x4 sa = {sym[0], sym[1], sym[2], sym[3]};
    f32x4 sb = {sym[4], sym[5], sym[6], sym[7]};
    f32x4 da = {deq[0], deq[1], deq[2], deq[3]};
    f32x4 db = {deq[4], deq[5], deq[6], deq[7]};
    s4[cA] = sa;
    s4[cB] = sb;
    d4[cA] = da;
    d4[cB] = db;
}

extern "C" void kernel_launch(void* const* d_in, const int* in_sizes, int n_in,
                              void* d_out, int out_size, void* d_ws, size_t ws_size,
                              hipStream_t stream) {
    const float* x        = (const float*)d_in[0];
    const float* means    = (const float*)d_in[1];
    const float* codebook = (const float*)d_in[2];

    int n     = in_sizes[0];       // 4,718,592
    int n4    = n >> 2;            // 1,179,648 float4 chunks
    int nwave = n4 >> 7;           // 9216 waves (128 chunks each)

    float* out_sym = (float*)d_out;        // first n floats: symbols (as float)
    float* out_deq = (float*)d_out + n;    // next n floats: dequant

    int block = 256;
    int grid  = (nwave * 64 + block - 1) / block;  // 2304 exactly

    quant_sos_kernel<<<grid, block, 0, stream>>>(x, means, codebook,
                                                 out_sym, out_deq, nwave);
}